// Round 13
// baseline (2567.522 us; speedup 1.0000x reference)
//
#include <hip/hip_runtime.h>
#include <math.h>

// T = 513 tokens, D=1024, H=16, HD=64, PAST=1024, Tkv=1537, L=16
#define KV_LS_STRIDE 1573888  // 1537*1024
#define KV_OUT_OFF 513
#define CLEN_OUT_IDX 50364929 // 513 + 16*2*1537*1024
#define VTP 1600              // vt16 row pitch (kt), covers kt<1600
#define KVL 1638400           // per-layer kb16 / vt16 stride (shorts)

typedef __attribute__((ext_vector_type(8))) short short8;
typedef __attribute__((ext_vector_type(4))) short short4v;
typedef __attribute__((ext_vector_type(4))) float f32x4;

static __device__ __forceinline__ float gelu_f(float v){
  return 0.5f * v * (1.0f + erff(v * 0.70710678118654752f));
}
static __device__ __forceinline__ unsigned short f2b(float f){
  unsigned int u = __float_as_uint(f);
  u += 0x7fffu + ((u>>16)&1u);
  return (unsigned short)(u>>16);
}
__device__ __forceinline__ void gload16(const void* g, void* l){
  __builtin_amdgcn_global_load_lds((const __attribute__((address_space(1))) void*)g,
                                   (__attribute__((address_space(3))) void*)l, 16, 0, 0);
}

__global__ __launch_bounds__(256) void copy_text_k(const float4* __restrict__ t,
                                                   float4* __restrict__ x){
  int i = blockIdx.x*256 + threadIdx.x;
  x[i] = t[i];
}

// K-split matvec: x[512,:] = prev(+nan->bos) @ Win + bin
__global__ __launch_bounds__(256) void build512_k(const float* __restrict__ prev,
    const float* __restrict__ bos, const float* __restrict__ Win,
    const float* __restrict__ bin, float* __restrict__ x){
  __shared__ float red[16][17];
  int t = threadIdx.x;
  int n = blockIdx.x*16 + (t&15), ks = t>>4;
  float s = 0.f;
  for (int k=ks*32; k<ks*32+32; ++k){
    float p = prev[k];
    if (p != p) p = bos[k];
    s += p * Win[(size_t)k*1024 + n];
  }
  red[ks][t&15] = s;
  __syncthreads();
  if (t < 16){
    float acc = bin[blockIdx.x*16 + t];
    #pragma unroll
    for (int j=0;j<16;++j) acc += red[j][t];
    x[(size_t)512*1024 + blockIdx.x*16 + t] = acc;
  }
}

__global__ __launch_bounds__(256) void rope_tab_k(float* __restrict__ cost,
    float* __restrict__ sint, const int* __restrict__ clen){
  int i = blockIdx.x*256 + threadIdx.x;
  if (i >= 513*32) return;
  int t = i >> 5, j = i & 31;
  float freq = expf((float)j * (-0.28782313662425572f));
  float ang = (float)(t + clen[0]) * freq;
  cost[i] = cosf(ang);
  sint[i] = sinf(ang);
}

// ---------- LayerNorm ----------
template<int BF16OUT>
__global__ __launch_bounds__(256) void ln_k(const float* __restrict__ x,
    const float* __restrict__ w, const float* __restrict__ b,
    float* __restrict__ outf, unsigned short* __restrict__ outh, int rows){
  int row = blockIdx.x; if (row >= rows) return;
  const float* xr = x + (size_t)row*1024;
  int tid = threadIdx.x;
  float4 v = *(const float4*)(xr + tid*4);
  float s  = v.x+v.y+v.z+v.w;
  float ss = v.x*v.x+v.y*v.y+v.z*v.z+v.w*v.w;
  for (int o=32;o;o>>=1){ s += __shfl_down(s,o); ss += __shfl_down(ss,o); }
  __shared__ float red[8];
  int wid = tid>>6;
  if ((tid&63)==0){ red[wid]=s; red[4+wid]=ss; }
  __syncthreads();
  if (tid==0){
    float ts = red[0]+red[1]+red[2]+red[3];
    float tss= red[4]+red[5]+red[6]+red[7];
    float mu = ts*(1.0f/1024.0f);
    float var= tss*(1.0f/1024.0f) - mu*mu;
    red[0]=mu; red[1]=rsqrtf(var + 1e-5f);
  }
  __syncthreads();
  float mu = red[0], rs = red[1];
  float4 wv = *(const float4*)(w + tid*4);
  float4 bv = *(const float4*)(b + tid*4);
  float4 o4;
  o4.x = (v.x-mu)*rs*wv.x + bv.x;
  o4.y = (v.y-mu)*rs*wv.y + bv.y;
  o4.z = (v.z-mu)*rs*wv.z + bv.z;
  o4.w = (v.w-mu)*rs*wv.w + bv.w;
  if (BF16OUT){
    uint2 u;
    u.x = (unsigned)f2b(o4.x) | ((unsigned)f2b(o4.y)<<16);
    u.y = (unsigned)f2b(o4.z) | ((unsigned)f2b(o4.w)<<16);
    *(uint2*)(outh + (size_t)row*1024 + tid*4) = u;
  } else {
    *(float4*)(outf + (size_t)row*1024 + tid*4) = o4;
  }
}

// ---------- batched weight transpose + bf16: W[l][K][N] -> Wt[l][N][K] ----------
__global__ __launch_bounds__(256) void wtrans_k(const float* __restrict__ W,
    unsigned short* __restrict__ Wt, int K, int N){
  __shared__ float s[64][68];
  int l = blockIdx.z;
  W  += (size_t)l*K*N;
  Wt += (size_t)l*N*K;
  int t = threadIdx.x;
  int n0 = blockIdx.x*64, k0 = blockIdx.y*64;
  int r = t>>4, c4 = (t&15)<<2;
  #pragma unroll
  for (int p=0;p<4;++p){
    float4 v = *(const float4*)(W + (size_t)(k0 + r + p*16)*N + n0 + c4);
    *(float4*)&s[r + p*16][c4] = v;
  }
  __syncthreads();
  int n = t>>2, ks = t&3;
  unsigned short tmp[16];
  #pragma unroll
  for (int j=0;j<16;++j) tmp[j] = f2b(s[ks*16 + j][n]);
  size_t ob = (size_t)(n0+n)*K + k0 + ks*16;
  uint4 lo, hi;
  lo.x = tmp[0] | ((unsigned)tmp[1]<<16);  lo.y = tmp[2] | ((unsigned)tmp[3]<<16);
  lo.z = tmp[4] | ((unsigned)tmp[5]<<16);  lo.w = tmp[6] | ((unsigned)tmp[7]<<16);
  hi.x = tmp[8] | ((unsigned)tmp[9]<<16);  hi.y = tmp[10]| ((unsigned)tmp[11]<<16);
  hi.z = tmp[12]| ((unsigned)tmp[13]<<16); hi.w = tmp[14]| ((unsigned)tmp[15]<<16);
  *(uint4*)(Wt + ob)     = lo;
  *(uint4*)(Wt + ob + 8) = hi;
}

// ---------- 64x64 tile, BK=128, K-split waves (each wave: full tile, 32-wide K-quarter)
// 2:1 MFMA:ds_read per wave (16 MFMA / 8 reads per K-step). Cross-wave reduction via LDS.
// MODE 0: fp32 partial -> P[z]; MODE 2: +bias+gelu -> bf16 outh;
// MODE 3: QKV fused epilogue (+bias, RoPE, q/k/v scatter, V-transpose).
template<int MODE>
__global__ __launch_bounds__(256,3) void mgemm64_k(const unsigned short* __restrict__ A,
    const unsigned short* __restrict__ Bt, float* __restrict__ P,
    const float* __restrict__ bias, unsigned short* __restrict__ outh,
    int M, int N, int K, int kc,
    const float* __restrict__ cost, const float* __restrict__ sint,
    unsigned short* __restrict__ qb16, unsigned short* __restrict__ kb16,
    unsigned short* __restrict__ vt, float* __restrict__ kl, float* __restrict__ vl){
  __shared__ __align__(16) unsigned short sbuf[16384];   // A: [0,8192) B: [8192,16384)
  int tid = threadIdx.x;
  int w = tid>>6, l = tid&63;
  int m0 = blockIdx.y*64, n0 = blockIdx.x*64;
  int k0 = blockIdx.z*kc, k1 = k0+kc;
  f32x4 acc[4][4];
  #pragma unroll
  for (int i=0;i<4;++i)
    #pragma unroll
    for (int j=0;j<4;++j) acc[i][j] = (f32x4){0.f,0.f,0.f,0.f};
  // staging: 16 chunks of 1KB each for A (4 rows x 256B); wave w handles chunks w*4+p.
  // lane l: row = chunk*4 + (l>>4); phys col shorts (l&15)*8; global col pre-swizzled
  // within its 64-short half: cg = half*64 + ((q ^ (row&7))*8).
  int lrow = l>>4, lc = l&15;
  int halfc = lc>>3, qc = lc&7;
  const unsigned short* gA[4]; const unsigned short* gB[4];
  unsigned short* lA[4]; unsigned short* lB[4];
  #pragma unroll
  for (int p=0;p<4;++p){
    int ch = w*4 + p;
    int rA = ch*4 + lrow;
    int colg = halfc*64 + ((qc ^ (rA&7))<<3);
    gA[p] = A  + (size_t)(m0 + rA)*K + colg;
    gB[p] = Bt + (size_t)(n0 + rA)*K + colg;
    lA[p] = &sbuf[ch*512];
    lB[p] = &sbuf[8192 + ch*512];
  }
  int lr = l&15, lg = l>>4;
  // read col: wave's K-quarter offset within 128, XOR-deswizzled
  int colr = ((w>>1)<<6) + ((((w&1)<<5) + (lg<<3)) ^ ((lr&7)<<3));
  for (int k=k0; k<k1; k+=128){
    #pragma unroll
    for (int p=0;p<4;++p) gload16(gA[p] + k, lA[p]);
    #pragma unroll
    for (int p=0;p<4;++p) gload16(gB[p] + k, lB[p]);
    __syncthreads();
    short8 af[4], bfr[4];
    #pragma unroll
    for (int mi=0;mi<4;++mi)
      af[mi] = *(const short8*)&sbuf[(mi*16+lr)*128 + colr];
    #pragma unroll
    for (int ni=0;ni<4;++ni)
      bfr[ni] = *(const short8*)&sbuf[8192 + (ni*16+lr)*128 + colr];
    #pragma unroll
    for (int mi=0;mi<4;++mi)
      #pragma unroll
      for (int ni=0;ni<4;++ni)
        acc[mi][ni] = __builtin_amdgcn_mfma_f32_16x16x32_bf16(af[mi], bfr[ni], acc[mi][ni], 0, 0, 0);
    __syncthreads();
  }
  // cross-wave K-reduction: waves 2,3 dump -> waves 0,1 add -> wave 1 dump -> wave 0 add
  float* redA = (float*)sbuf;            // 64*64 fp32 = 16KB
  float* redB = (float*)(sbuf + 8192);
  if (w == 2){
    #pragma unroll
    for (int mi=0;mi<4;++mi)
      #pragma unroll
      for (int ni=0;ni<4;++ni)
        #pragma unroll
        for (int r=0;r<4;++r)
          redA[(mi*16+lg*4+r)*64 + ni*16+lr] = acc[mi][ni][r];
  } else if (w == 3){
    #pragma unroll
    for (int mi=0;mi<4;++mi)
      #pragma unroll
      for (int ni=0;ni<4;++ni)
        #pragma unroll
        for (int r=0;r<4;++r)
          redB[(mi*16+lg*4+r)*64 + ni*16+lr] = acc[mi][ni][r];
  }
  __syncthreads();
  if (w == 0){
    #pragma unroll
    for (int mi=0;mi<4;++mi)
      #pragma unroll
      for (int ni=0;ni<4;++ni)
        #pragma unroll
        for (int r=0;r<4;++r)
          acc[mi][ni][r] += redA[(mi*16+lg*4+r)*64 + ni*16+lr];
  } else if (w == 1){
    #pragma unroll
    for (int mi=0;mi<4;++mi)
      #pragma unroll
      for (int ni=0;ni<4;++ni)
        #pragma unroll
        for (int r=0;r<4;++r)
          acc[mi][ni][r] += redB[(mi*16+lg*4+r)*64 + ni*16+lr];
  }
  __syncthreads();
  if (w == 1){
    #pragma unroll
    for (int mi=0;mi<4;++mi)
      #pragma unroll
      for (int ni=0;ni<4;++ni)
        #pragma unroll
        for (int r=0;r<4;++r)
          redA[(mi*16+lg*4+r)*64 + ni*16+lr] = acc[mi][ni][r];
  }
  __syncthreads();
  if (w != 0) return;
  #pragma unroll
  for (int mi=0;mi<4;++mi)
    #pragma unroll
    for (int ni=0;ni<4;++ni)
      #pragma unroll
      for (int r=0;r<4;++r)
        acc[mi][ni][r] += redA[(mi*16+lg*4+r)*64 + ni*16+lr];

  if constexpr (MODE==3){
    int nt = n0 >> 6;          // 0..47
    int kind = nt >> 4;        // 0=q 1=k 2=v
    int hh = nt & 15;
    #pragma unroll
    for (int mi=0;mi<4;++mi){
      int rb = m0 + mi*16 + lg*4;
      #pragma unroll
      for (int ni=0;ni<4;++ni){
        int d = ni*16 + lr;
        float bcol = bias[n0 + d];
        if (kind == 2){
          unsigned short pk[4];
          #pragma unroll
          for (int r=0;r<4;++r){
            float v = acc[mi][ni][r] + bcol;
            pk[r] = f2b(v);
            int t = rb + r;
            if (t < 513) vl[(size_t)(1024+t)*1024 + hh*64 + d] = v;
          }
          uint2 u2;
          u2.x = pk[0] | ((unsigned)pk[1]<<16);
          u2.y = pk[2] | ((unsigned)pk[3]<<16);
          *(uint2*)(vt + (size_t)(hh*64+d)*VTP + 1024 + rb) = u2;  // pad absorbs t>=513
        } else {
          int j = d >> 1;
          #pragma unroll
          for (int r=0;r<4;++r){
            float v = acc[mi][ni][r] + bcol;
            float p = __shfl_xor(v, 1);   // partner d^1 in lane lr^1 (wave0 all active)
            int t = rb + r;
            int tc = (t < 513) ? t : 0;
            float c = cost[(tc<<5)+j], s = sint[(tc<<5)+j];
            float o = (d&1) ? (p*s + v*c) : (v*c - p*s);
            if (t < 513){
              if (kind == 0){
                qb16[(size_t)t*1024 + hh*64 + d] = f2b(o*0.125f);
              } else {
                size_t ko = (size_t)(1024+t)*1024 + hh*64 + d;
                kb16[ko] = f2b(o);
                kl[ko] = o;
              }
            }
          }
        }
      }
    }
  } else {
    float* Pz = P + (size_t)blockIdx.z*M*N;
    #pragma unroll
    for (int mi=0;mi<4;++mi){
      int rb = m0 + mi*16 + lg*4;
      #pragma unroll
      for (int ni=0;ni<4;++ni){
        int col = n0 + ni*16 + lr;
        float bcol = (MODE!=0) ? bias[col] : 0.f;
        #pragma unroll
        for (int r=0;r<4;++r){
          int row = rb + r;
          if (row < M){
            if constexpr (MODE==0){
              Pz[(size_t)row*N + col] = acc[mi][ni][r];
            } else {
              outh[(size_t)row*N + col] = f2b(gelu_f(acc[mi][ni][r] + bcol));
            }
          }
        }
      }
    }
  }
}

// ---------- split-K reduce + bias + residual(+LN->bf16); one block per row ----------
template<int KS, int DOLN>
__global__ __launch_bounds__(256) void reduce_ln_k(const float* __restrict__ P,
    const float* __restrict__ bias, float* __restrict__ x,
    const float* __restrict__ lnw, const float* __restrict__ lnb,
    unsigned short* __restrict__ outh){
  const int M = 513;
  int row = blockIdx.x;
  int tid = threadIdx.x;
  int c4 = tid<<2;
  float4 sv = *(const float4*)(P + (size_t)row*1024 + c4);
  #pragma unroll
  for (int z=1; z<KS; ++z){
    float4 t = *(const float4*)(P + (size_t)z*M*1024 + (size_t)row*1024 + c4);
    sv.x+=t.x; sv.y+=t.y; sv.z+=t.z; sv.w+=t.w;
  }
  float4 bv = *(const float4*)(bias + c4);
  float4 xv = *(const float4*)(x + (size_t)row*1024 + c4);
  xv.x += sv.x+bv.x; xv.y += sv.y+bv.y; xv.z += sv.z+bv.z; xv.w += sv.w+bv.w;
  *(float4*)(x + (size_t)row*1024 + c4) = xv;
  if constexpr (DOLN){
    float s  = xv.x+xv.y+xv.z+xv.w;
    float ss = xv.x*xv.x+xv.y*xv.y+xv.z*xv.z+xv.w*xv.w;
    for (int o=32;o;o>>=1){ s += __shfl_down(s,o); ss += __shfl_down(ss,o); }
    __shared__ float red[8];
    int wid = tid>>6;
    if ((tid&63)==0){ red[wid]=s; red[4+wid]=ss; }
    __syncthreads();
    if (tid==0){
      float ts = red[0]+red[1]+red[2]+red[3];
      float tss= red[4]+red[5]+red[6]+red[7];
      float mu = ts*(1.0f/1024.0f);
      float var= tss*(1.0f/1024.0f) - mu*mu;
      red[0]=mu; red[1]=rsqrtf(var + 1e-5f);
    }
    __syncthreads();
    float mu = red[0], rs = red[1];
    float4 wv = *(const float4*)(lnw + c4);
    float4 bb = *(const float4*)(lnb + c4);
    float o0 = (xv.x-mu)*rs*wv.x + bb.x;
    float o1 = (xv.y-mu)*rs*wv.y + bb.y;
    float o2 = (xv.z-mu)*rs*wv.z + bb.z;
    float o3 = (xv.w-mu)*rs*wv.w + bb.w;
    uint2 u;
    u.x = (unsigned)f2b(o0) | ((unsigned)f2b(o1)<<16);
    u.y = (unsigned)f2b(o2) | ((unsigned)f2b(o3)<<16);
    *(uint2*)(outh + (size_t)row*1024 + c4) = u;
  }
}

// ---------- BATCHED past KV: bf16 K buf + transposed V buf + fp32 cache-out ----------
__global__ __launch_bounds__(256) void past16_k(const float* __restrict__ kvin,
    unsigned short* __restrict__ kb, unsigned short* __restrict__ vt,
    float* __restrict__ kvout){
  __shared__ float s[64][68];
  int l = blockIdx.z;
  int hh = blockIdx.x, t0 = blockIdx.y*64;
  const float* kvK = kvin + (size_t)l*2097152;
  const float* kvV = kvK + 1048576;
  unsigned short* kbL = kb + (size_t)l*KVL;
  unsigned short* vtL = vt + (size_t)l*KVL;
  float* kl = kvout + (size_t)(2*l)  *KV_LS_STRIDE;
  float* vl = kvout + (size_t)(2*l+1)*KV_LS_STRIDE;
  int tid = threadIdx.x;
  int row = tid>>4, c4 = (tid&15)<<2;
  #pragma unroll
  for (int p=0;p<4;++p){
    int rr = row + p*16;
    size_t off = (size_t)(t0+rr)*1024 + hh*64 + c4;
    float4 v = *(const float4*)(kvK + off);
    uint2 u;
    u.x = (unsigned)f2b(v.x) | ((unsigned)f2b(v.y)<<16);
    u.y = (unsigned)f2b(v.z) | ((unsigned)f2b(v.w)<<16);
    *(uint2*)(kbL + off) = u;
    kl[off]=v.x; kl[off+1]=v.y; kl[off+2]=v.z; kl[off+3]=v.w;
    float4 w = *(const float4*)(kvV + off);
    *(float4*)&s[rr][c4] = w;
    vl[off]=w.x; vl[off+1]=w.y; vl[off+2]=w.z; vl[off+3]=w.w;
  }
  __syncthreads();
  int n = tid>>2, ks = tid&3;
  unsigned short tmp[16];
  #pragma unroll
  for (int j=0;j<16;++j) tmp[j] = f2b(s[ks*16+j][n]);
  size_t ob = (size_t)(hh*64+n)*VTP + t0 + ks*16;
  uint4 lo, hi;
  lo.x = tmp[0] | ((unsigned)tmp[1]<<16);  lo.y = tmp[2] | ((unsigned)tmp[3]<<16);
  lo.z = tmp[4] | ((unsigned)tmp[5]<<16);  lo.w = tmp[6] | ((unsigned)tmp[7]<<16);
  hi.x = tmp[8] | ((unsigned)tmp[9]<<16);  hi.y = tmp[10]| ((unsigned)tmp[11]<<16);
  hi.z = tmp[12]| ((unsigned)tmp[13]<<16); hi.w = tmp[14]| ((unsigned)tmp[15]<<16);
  *(uint4*)(vtL + ob)     = lo;
  *(uint4*)(vtL + ob + 8) = hi;
}

// ---------- MFMA flash attention: zero-LDS, swapped-operand, packed K=32 PV ----------
static __device__ __forceinline__ f32x4 mfma32(short8 a, short8 b, f32x4 c){
  return __builtin_amdgcn_mfma_f32_16x16x32_bf16(a, b, c, 0, 0, 0);
}

__global__ __launch_bounds__(128) void attn_k(const unsigned short* __restrict__ qb,
    const unsigned short* __restrict__ kb, const unsigned short* __restrict__ vt,
    float* __restrict__ Oc, float* __restrict__ ml){
  const int T=513, Tkv=1537, past=1024;
  int hh = blockIdx.x, bt = blockIdx.y, ch = blockIdx.z;
  int wv = threadIdx.x >> 6, l = threadIdx.x & 63;
  int g = l >> 4, lr = l & 15;
  int q0 = bt*32 + wv*16;
  int gq = q0 + lr;
  const unsigned short* qp = qb + (size_t)gq*1024 + hh*64 + g*8;
  short8 qf0 = *(const short8*)qp;
  short8 qf1 = *(const short8*)(qp+32);
  f32x4 acc_o[4];
  #pragma unroll
  for (int i=0;i<4;++i) acc_o[i] = (f32x4){0.f,0.f,0.f,0.f};
  float m_run = -1e30f, l_run = 0.f;
  int kend_w = past + q0 + 16; if (kend_w > Tkv) kend_w = Tkv;
  int kstart = ch*384;
  int kend = (ch==3) ? kend_w : ((ch+1)*384 < kend_w ? (ch+1)*384 : kend_w);
  for (int kt0 = kstart; kt0 < kend; kt0 += 64){
    float p[16];
    #pragma unroll
    for (int st=0; st<4; ++st){
      const unsigned short* kp = kb + (size_t)(kt0+st*16+lr)*1024 + hh*64 + g*8;
      short8 kf0 = *(const short8*)kp;
      short8 kf1 = *(const short8*)(kp+32);
      f32x4 s4 = (f32x4){0.f,0.f,0.f,0.f};
      s4 = mfma32(kf0, qf0, s4);
      s4 = mfma32(kf1, qf1, s4);
      #pragma unroll
      for (int r=0;r<4;++r) p[st*4+r] = s4[r];
    }
    if (kt0 + 63 > past + q0 + 15 || kt0 + 63 >= Tkv){
      #pragma unroll
      for (int st=0; st<4; ++st)
        #pragma unroll
        for (int r=0;r<4;++r){
          int kt = kt0 + st*16 + g*4 + r;
          if (kt > past + gq || kt >= Tkv) p[st*4+r] = -1e30f;
        }
    }
    float tmax = p[0];
    #pragma unroll
    for (int i=1;i<16;++i) tmax = fmaxf(tmax, p[i]);
    tmax = fmaxf(tmax, __shfl_xor(tmax,16));
    tmax = fmaxf(tmax, __shfl_xor(tmax,32));
    float m_new = fmaxf(m_run, tmax);
    float sc = __expf(m_run - m_new);
    float psum = 0.f;
    #pragma unroll
    for (int i=0;i<16;++i){ p[i] = __expf(p[i] - m_new); psum += p[i]; }
    psum += __shfl_xor(psum,16); psum += __shfl_xor(psum,32);
    l_run = l_run*sc + psum;
    m_run = m_new;
    #pragma unroll
    for (int db=0;db<4;++db){
      acc_o[db][0]*=sc; acc_o[db][1]*=sc; acc_o[db][2]*=sc; acc_o[db][3]*=sc;
    }
    short8 pf[2];
    #pragma unroll
    for (int sp=0; sp<2; ++sp){
      union { short8 s8; unsigned int u[4]; } pu;
      pu.u[0] = (unsigned)f2b(p[sp*8+0]) | ((unsigned)f2b(p[sp*8+1])<<16);
      pu.u[1] = (unsigned)f2b(p[sp*8+2]) | ((unsigned)f2b(p[sp*8+3])<<16);
      pu.u[2] = (unsigned)f2b(p[sp*8+4]) | ((unsigned)f2b(p[sp*8+5])<<16);
      pu.u[3] = (unsigned)f2b(p[sp*8+6]) | ((unsigned)f2b(p[sp*8+7])<<16);
      pf[sp] = pu.s8;
    }
    #pragma unroll
    for (int sp=0; sp<2; ++sp){
      #pragma unroll
      for (int db=0; db<4; ++db){
        const unsigned short* vp = vt + (size_t)(hh*64 + db*16 + lr)*VTP + kt0 + sp*32 + g*4;
        short4v va0 = *(const short4v*)vp;
        short4v va1 = *(const short4v*)(vp + 16);
        short8 va = (short8){va0[0],va0[1],va0[2],va0[3],va1[0],va1[1],va1[2],va1[3]};
        acc_o[db] = mfma32(va, pf[sp], acc_o[db]);
      }
    }
  }
  if (gq < T){
    size_t ob = ((size_t)(ch*16+hh)*544 + gq)*64;
    #pragma unroll
    for (int db=0;db<4;++db)
      *(float4*)(Oc + ob + db*16 + g*4) = make_float4(acc_o[db][0],acc_o[db][1],acc_o[db][2],acc_o[db][3]);
    if (g==0){
      size_t mo = ((size_t)(ch*16+hh)*544 + gq)*2;
      ml[mo] = m_run; ml[mo+1] = l_run;
    }
  }
}

// ---------- combine 4 KV chunks -> bf16 attn out ----------
__global__ __launch_bounds__(256) void attn_comb_k(const float* __restrict__ Oc,
    const float* __restrict__ ml, unsigned short* __restrict__ obb){
  int qg = blockIdx.x;
  int t = threadIdx.x;
  int hh = t>>4, d4 = (t&15)<<2;
  float m[4], lv[4];
  float mm = -1e30f;
  #pragma unroll
  for (int c=0;c<4;++c){
    size_t mo = ((size_t)(c*16+hh)*544 + qg)*2;
    m[c]=ml[mo]; lv[c]=ml[mo+1];
    mm = fmaxf(mm, m[c]);
  }
  float w[4], denom = 0.f;
  #pragma unroll
  for (int c=0;c<4;++c){ w[c] = __expf(m[c]-mm); denom += lv[c]*w[c]; }
  float inv = 1.0f/denom;
  float r0=0.f,r1=0.f,r2=0.f,r3=0.f;
  #pragma unroll
  for (int c=0;c<4;++c){
    float4 o = *(const float4*)(Oc + (((size_t)(c*16+hh)*544+qg)*64 + d4));
    r0 += o.x*w[c]; r1 += o.y*w[c]; r2 += o.z*w[c]; r3 += o.w*w[c];
  }
  r0*=inv; r1*=inv; r2*=inv; r3*=inv;
  uint2 u;
  u.x = (unsigned)f2b(r0) | ((unsigned)f2b(r1)<<16);
  u.y = (unsigned)f2b(r2) | ((unsigned)f2b(r3)<<16);
  *(uint2*)(obb + (size_t)qg*1024 + hh*64 + d4) = u;
}

// ---------- eos head + cache_len ----------
__global__ __launch_bounds__(256) void eos_tail_k(const float* __restrict__ tout,
    const float* __restrict__ Weos, const float* __restrict__ beos,
    const int* __restrict__ clen, float* __restrict__ out){
  int tid = threadIdx.x;
  float s = 0.f;
  for (int i=tid;i<1024;i+=256) s += tout[i]*Weos[i];
  for (int o=32;o;o>>=1) s += __shfl_down(s,o);
  __shared__ float red[4];
  if ((tid&63)==0) red[tid>>6] = s;
  __syncthreads();
  if (tid==0){
    float v = red[0]+red[1]+red[2]+red[3] + beos[0];
    out[512] = (v > -4.0f) ? 1.0f : 0.0f;
    out[CLEN_OUT_IDX] = (float)(clen[0] + 513);
  }
}

// ---------- flow MLP (K-split) ----------
__global__ __launch_bounds__(256) void flow1_k(const float* __restrict__ tout,
    const float* __restrict__ noise, const float* __restrict__ Wf1,
    const float* __restrict__ bf1, float* __restrict__ fh){
  __shared__ float red[16][17];
  int t = threadIdx.x;
  int n = blockIdx.x*16 + (t&15), ks = t>>4;
  float s = 0.f;
  for (int k=ks*96; k<ks*96+96; ++k){
    float in = (k < 1024) ? tout[k] : noise[k-1024];
    size_t krow = (k < 1024) ? (size_t)k : (size_t)(k+2);
    s += in * Wf1[krow*2048 + n];
  }
  red[ks][t&15] = s;
  __syncthreads();
  if (t < 16){
    int nn = blockIdx.x*16 + t;
    float acc = bf1[nn] + Wf1[(size_t)1025*2048 + nn];  // t_time=1
    #pragma unroll
    for (int j=0;j<16;++j) acc += red[j][t];
    fh[nn] = gelu_f(acc);
  }
}

__global__ __launch_bounds__(256) void flow2_k(const float* __restrict__ fh,
    const float* __restrict__ noise, const float* __restrict__ Wf2,
    const float* __restrict__ bf2, float* __restrict__ out){
  __shared__ float red[16][17];
  int t = threadIdx.x;
  int n = blockIdx.x*16 + (t&15), ks = t>>4;
  float s = 0.f;
  for (int k=ks*128; k<ks*128+128; ++k) s += fh[k]*Wf2[(size_t)k*512 + n];
  red[ks][t&15] = s;
  __syncthreads();
  if (t < 16){
    int nn = blockIdx.x*16 + t;
    float acc = bf2[nn];
    #pragma unroll
    for (int j=0;j<16;++j) acc += red[j][t];
    out[nn] = noise[nn] + acc;
  }
}

extern "C" void kernel_launch(void* const* d_in, const int* in_sizes, int n_in,
                              void* d_out, int out_size, void* d_ws, size_t ws_size,
                              hipStream_t stream) {
  const float* text  = (const float*)d_in[0];
  const float* prevl = (const float*)d_in[1];
  const float* kvin  = (const float*)d_in[2];
  const int*   clen  = (const int*)  d_in[3];
  const float* noise = (const float*)d_in[4];
  const float* bos   = (const float*)d_in[5];
  const float* Win   = (const float*)d_in[6];
  const float* bin   = (const float*)d_in[7];
  const float* ln1w  = (const float*)d_in[8];
  const float* ln1b  = (const float*)d_in[9];
  const float* Wqkv  = (const float*)d_in[10];
  const float* bqkv  = (const float*)d_in[11];
  const float* Wo    = (const float*)d_in[12];
  const float* bo    = (const float*)d_in[13];
  const float* ln2w  = (const float*)d_in[14];
  const float* ln2b  = (const float*)d_in[15];
  const float* W1    = (const float*)d_in[16];
  const float* b1    = (const float*)d_in[17];
  const float* W2    = (const float*)d_in[18];
  const float* b2    = (const float*)d_in[19];
  const float* onw   = (const float*)d_in[20];
  const float* onb   = (const float*)d_in[21];
  const float* Weos  = (const float*)d_in[22];
  const float* beos  = (const float*)d_in[23];
  const float* Wf1   = (const float*)d_in[24];
  const float* bf1   = (const float*)d_in[25];
  const float* Wf2   = (const float*)d_in[26];
  const float* bf2   = (const float*)d_in[27];

  float* out   = (float*)d_out;
  float* kvout = out + KV_OUT_OFF;
  float* ws = (float*)d_ws;
  float* x    = ws;                          // 525312
  float* Pbuf = x    + 525312;               // 4202496
  float* Oc   = Pbuf + 4202496;              // 2228224
  float* mlb  = Oc   + 2228224;              // 69632
  float* cost = mlb  + 69632;                // 16416
  float* sint = cost + 16416;                // 16416
  float* tout = sint + 16416;                // 1024
  float* fh   = tout + 1024;                 // 2048
  unsigned short* hb   = (unsigned short*)(fh + 2048); // 640*1024
  unsigned short* gb   = hb   + 655360;      // 640*4096
  unsigned short* obb  = gb   + 2621440;     // 640*1024
  unsigned short* qb16 = obb  + 655360;      // 544*1024
  unsigned short* kb16 = qb16 + 557056;      // 16 * KVL
  unsigned short* vt16 = kb16 + (size_t)16*KVL;
  unsigned short* qkvT = vt16 + (size_t)16*KVL;          // 16*3072*1024
  unsigned short* woT  = qkvT + (size_t)16*3145728;      // 16*1024*1024
  unsigned short* w1T  = woT  + (size_t)16*1048576;      // 16*4096*1024
  unsigned short* w2T  = w1T  + (size_t)16*4194304;      // 16*1024*4096

  // prologue
  past16_k<<<dim3(16,16,16),256,0,stream>>>(kvin, kb16, vt16, kvout);
  wtrans_k<<<dim3(48,16,16),256,0,stream>>>(Wqkv, qkvT, 1024, 3072);
  wtrans_k<<<dim3(16,16,16),256,0,stream>>>(Wo,   woT,  1024, 1024);
  wtrans_k<<<dim3(64,16,16),256,0,stream>>>(W1,   w1T,  1024, 4096);
  wtrans_k<<<dim3(16,64,16),256,0,stream>>>(W2,   w2T,  4096, 1024);
  copy_text_k<<<512,256,0,stream>>>((const float4*)text, (float4*)x);
  build512_k<<<64,256,0,stream>>>(prevl, bos, Win, bin, x);
  rope_tab_k<<<65,256,0,stream>>>(cost, sint, clen);
  ln_k<1><<<513,256,0,stream>>>(x, ln1w, ln1b, nullptr, hb, 513);

  for (int l=0; l<16; ++l){
    float* kl = kvout + (size_t)(2*l)  *KV_LS_STRIDE;
    float* vl = kvout + (size_t)(2*l+1)*KV_LS_STRIDE;
    unsigned short* kbL = kb16 + (size_t)l*KVL;
    unsigned short* vtL = vt16 + (size_t)l*KVL;
    // QKV: fused RoPE/scatter/V-transpose epilogue (MODE 3), 432 blocks
    mgemm64_k<3><<<dim3(48,9),256,0,stream>>>(hb, qkvT+(size_t)l*3145728, nullptr,
        bqkv+(size_t)l*3072, nullptr, 513, 3072, 1024, 1024,
        cost, sint, qb16, kbL, vtL, kl, vl);
    attn_k<<<dim3(16,17,4),128,0,stream>>>(qb16, kbL, vtL, Oc, mlb);
    attn_comb_k<<<513,256,0,stream>>>(Oc, mlb, obb);
    // Wo: split-K=4 (576 blocks) + reduce+residual+LN2
    mgemm64_k<0><<<dim3(16,9,4),256,0,stream>>>(obb, woT+(size_t)l*1048576, Pbuf,
        nullptr, nullptr, 513, 1024, 1024, 256,
        nullptr, nullptr, nullptr, nullptr, nullptr, nullptr, nullptr);
    reduce_ln_k<4,1><<<513,256,0,stream>>>(Pbuf, bo+(size_t)l*1024, x,
        ln2w+(size_t)l*1024, ln2b+(size_t)l*1024, hb);
    // FF1: full-K + bias + gelu -> gb bf16 (576 blocks)
    mgemm64_k<2><<<dim3(64,9),256,0,stream>>>(hb, w1T+(size_t)l*4194304, nullptr,
        b1+(size_t)l*4096, gb, 513, 4096, 1024, 1024,
        nullptr, nullptr, nullptr, nullptr, nullptr, nullptr, nullptr);
    // FF2: split-K=4 (576 blocks) + reduce+residual+next LN1
    mgemm64_k<0><<<dim3(16,9,4),256,0,stream>>>(gb, w2T+(size_t)l*4194304, Pbuf,
        nullptr, nullptr, 513, 1024, 4096, 1024,
        nullptr, nullptr, nullptr, nullptr, nullptr, nullptr, nullptr);
    if (l < 15)
      reduce_ln_k<4,1><<<513,256,0,stream>>>(Pbuf, b2+(size_t)l*1024, x,
          ln1w+(size_t)(l+1)*1024, ln1b+(size_t)(l+1)*1024, hb);
    else
      reduce_ln_k<4,0><<<513,256,0,stream>>>(Pbuf, b2+(size_t)l*1024, x,
          nullptr, nullptr, nullptr);
  }

  ln_k<0><<<1,256,0,stream>>>(x + (size_t)512*1024, onw, onb, tout, nullptr, 1);
  eos_tail_k<<<1,256,0,stream>>>(tout, Weos, beos, clen, out);
  flow1_k<<<128,256,0,stream>>>(tout, noise, Wf1, bf1, fh);
  flow2_k<<<32,256,0,stream>>>(fh, noise, Wf2, bf2, out);
}

// Round 14
// 2288.296 us; speedup vs baseline: 1.1220x; 1.1220x over previous
//
#include <hip/hip_runtime.h>
#include <math.h>

// T = 513 tokens, D=1024, H=16, HD=64, PAST=1024, Tkv=1537, L=16
#define KV_LS_STRIDE 1573888  // 1537*1024
#define KV_OUT_OFF 513
#define CLEN_OUT_IDX 50364929 // 513 + 16*2*1537*1024
#define VTP 1600              // vt16 row pitch (kt), covers kt<1600
#define KVL 1638400           // per-layer kb16 / vt16 stride (shorts)
#define NCH 6                 // attn kv chunks

typedef __attribute__((ext_vector_type(8))) short short8;
typedef __attribute__((ext_vector_type(4))) short short4v;
typedef __attribute__((ext_vector_type(4))) float f32x4;

static __device__ __forceinline__ float gelu_f(float v){
  return 0.5f * v * (1.0f + erff(v * 0.70710678118654752f));
}
static __device__ __forceinline__ unsigned short f2b(float f){
  unsigned int u = __float_as_uint(f);
  u += 0x7fffu + ((u>>16)&1u);
  return (unsigned short)(u>>16);
}
__device__ __forceinline__ void gload16(const void* g, void* l){
  __builtin_amdgcn_global_load_lds((const __attribute__((address_space(1))) void*)g,
                                   (__attribute__((address_space(3))) void*)l, 16, 0, 0);
}

__global__ __launch_bounds__(256) void copy_text_k(const float4* __restrict__ t,
                                                   float4* __restrict__ x){
  int i = blockIdx.x*256 + threadIdx.x;
  x[i] = t[i];
}

// K-split matvec: x[512,:] = prev(+nan->bos) @ Win + bin
__global__ __launch_bounds__(256) void build512_k(const float* __restrict__ prev,
    const float* __restrict__ bos, const float* __restrict__ Win,
    const float* __restrict__ bin, float* __restrict__ x){
  __shared__ float red[16][17];
  int t = threadIdx.x;
  int n = blockIdx.x*16 + (t&15), ks = t>>4;
  float s = 0.f;
  for (int k=ks*32; k<ks*32+32; ++k){
    float p = prev[k];
    if (p != p) p = bos[k];
    s += p * Win[(size_t)k*1024 + n];
  }
  red[ks][t&15] = s;
  __syncthreads();
  if (t < 16){
    float acc = bin[blockIdx.x*16 + t];
    #pragma unroll
    for (int j=0;j<16;++j) acc += red[j][t];
    x[(size_t)512*1024 + blockIdx.x*16 + t] = acc;
  }
}

__global__ __launch_bounds__(256) void rope_tab_k(float* __restrict__ cost,
    float* __restrict__ sint, const int* __restrict__ clen){
  int i = blockIdx.x*256 + threadIdx.x;
  if (i >= 513*32) return;
  int t = i >> 5, j = i & 31;
  float freq = expf((float)j * (-0.28782313662425572f));
  float ang = (float)(t + clen[0]) * freq;
  cost[i] = cosf(ang);
  sint[i] = sinf(ang);
}

// ---------- LayerNorm ----------
template<int BF16OUT>
__global__ __launch_bounds__(256) void ln_k(const float* __restrict__ x,
    const float* __restrict__ w, const float* __restrict__ b,
    float* __restrict__ outf, unsigned short* __restrict__ outh, int rows){
  int row = blockIdx.x; if (row >= rows) return;
  const float* xr = x + (size_t)row*1024;
  int tid = threadIdx.x;
  float4 v = *(const float4*)(xr + tid*4);
  float s  = v.x+v.y+v.z+v.w;
  float ss = v.x*v.x+v.y*v.y+v.z*v.z+v.w*v.w;
  for (int o=32;o;o>>=1){ s += __shfl_down(s,o); ss += __shfl_down(ss,o); }
  __shared__ float red[8];
  int wid = tid>>6;
  if ((tid&63)==0){ red[wid]=s; red[4+wid]=ss; }
  __syncthreads();
  if (tid==0){
    float ts = red[0]+red[1]+red[2]+red[3];
    float tss= red[4]+red[5]+red[6]+red[7];
    float mu = ts*(1.0f/1024.0f);
    float var= tss*(1.0f/1024.0f) - mu*mu;
    red[0]=mu; red[1]=rsqrtf(var + 1e-5f);
  }
  __syncthreads();
  float mu = red[0], rs = red[1];
  float4 wv = *(const float4*)(w + tid*4);
  float4 bv = *(const float4*)(b + tid*4);
  float4 o4;
  o4.x = (v.x-mu)*rs*wv.x + bv.x;
  o4.y = (v.y-mu)*rs*wv.y + bv.y;
  o4.z = (v.z-mu)*rs*wv.z + bv.z;
  o4.w = (v.w-mu)*rs*wv.w + bv.w;
  if (BF16OUT){
    uint2 u;
    u.x = (unsigned)f2b(o4.x) | ((unsigned)f2b(o4.y)<<16);
    u.y = (unsigned)f2b(o4.z) | ((unsigned)f2b(o4.w)<<16);
    *(uint2*)(outh + (size_t)row*1024 + tid*4) = u;
  } else {
    *(float4*)(outf + (size_t)row*1024 + tid*4) = o4;
  }
}

// ---------- batched weight transpose + bf16: W[l][K][N] -> Wt[l][N][K] ----------
__global__ __launch_bounds__(256) void wtrans_k(const float* __restrict__ W,
    unsigned short* __restrict__ Wt, int K, int N){
  __shared__ float s[64][68];
  int l = blockIdx.z;
  W  += (size_t)l*K*N;
  Wt += (size_t)l*N*K;
  int t = threadIdx.x;
  int n0 = blockIdx.x*64, k0 = blockIdx.y*64;
  int r = t>>4, c4 = (t&15)<<2;
  #pragma unroll
  for (int p=0;p<4;++p){
    float4 v = *(const float4*)(W + (size_t)(k0 + r + p*16)*N + n0 + c4);
    *(float4*)&s[r + p*16][c4] = v;
  }
  __syncthreads();
  int n = t>>2, ks = t&3;
  unsigned short tmp[16];
  #pragma unroll
  for (int j=0;j<16;++j) tmp[j] = f2b(s[ks*16 + j][n]);
  size_t ob = (size_t)(n0+n)*K + k0 + ks*16;
  uint4 lo, hi;
  lo.x = tmp[0] | ((unsigned)tmp[1]<<16);  lo.y = tmp[2] | ((unsigned)tmp[3]<<16);
  lo.z = tmp[4] | ((unsigned)tmp[5]<<16);  lo.w = tmp[6] | ((unsigned)tmp[7]<<16);
  hi.x = tmp[8] | ((unsigned)tmp[9]<<16);  hi.y = tmp[10]| ((unsigned)tmp[11]<<16);
  hi.z = tmp[12]| ((unsigned)tmp[13]<<16); hi.w = tmp[14]| ((unsigned)tmp[15]<<16);
  *(uint4*)(Wt + ob)     = lo;
  *(uint4*)(Wt + ob + 8) = hi;
}

// ---------- 64x64x64 bf16 MFMA GEMM, 4 waves, XOR-swizzled LDS, 2-phase dbuf ----------
// MODE 0: fp32 partial -> P[z]; MODE 2: +bias+gelu -> bf16 outh;
// MODE 3: QKV fused epilogue (+bias, RoPE, q/k/v scatter, V-transpose).
template<int MODE>
__global__ __launch_bounds__(256,4) void mgemm64_k(const unsigned short* __restrict__ A,
    const unsigned short* __restrict__ Bt, float* __restrict__ P,
    const float* __restrict__ bias, unsigned short* __restrict__ outh,
    int M, int N, int K, int kc,
    const float* __restrict__ cost, const float* __restrict__ sint,
    unsigned short* __restrict__ qb16, unsigned short* __restrict__ kb16,
    unsigned short* __restrict__ vt, float* __restrict__ kl, float* __restrict__ vl){
  __shared__ unsigned short Alds[2][64*64];
  __shared__ unsigned short Blds[2][64*64];
  int tid = threadIdx.x;
  int w = tid>>6, l = tid&63;
  int m0 = blockIdx.y*64, n0 = blockIdx.x*64;
  int k0 = blockIdx.z*kc, k1 = k0+kc;
  f32x4 acc[2][2];
  #pragma unroll
  for (int i=0;i<2;++i)
    #pragma unroll
    for (int j=0;j<2;++j) acc[i][j] = (f32x4){0.f,0.f,0.f,0.f};
  int srow = l>>3;
  int scol = (((l&7) ^ (srow&7)))*8;
  const unsigned short* ga  = A  + (size_t)(m0 + w*16 + srow)*K + scol;
  const unsigned short* gbp = Bt + (size_t)(n0 + w*16 + srow)*K + scol;
  int lofs = w*16*64;
  int wr = w>>1, wc = w&1, lr = l&15, lg = l>>4;
  int sw = (lr&7)<<3;
  gload16(ga + k0,                &Alds[0][lofs]);
  gload16(ga + (size_t)8*K + k0,  &Alds[0][lofs + 512]);
  gload16(gbp + k0,               &Blds[0][lofs]);
  gload16(gbp + (size_t)8*K + k0, &Blds[0][lofs + 512]);
  __syncthreads();
  int cur = 0;
  for (int k=k0; k<k1; k+=64){
    if (k + 64 < k1){
      int nb = cur^1, kn = k + 64;
      gload16(ga + kn,                &Alds[nb][lofs]);
      gload16(ga + (size_t)8*K + kn,  &Alds[nb][lofs + 512]);
      gload16(gbp + kn,               &Blds[nb][lofs]);
      gload16(gbp + (size_t)8*K + kn, &Blds[nb][lofs + 512]);
    }
    const unsigned short* la = &Alds[cur][0];
    const unsigned short* lb = &Blds[cur][0];
    #pragma unroll
    for (int kk=0; kk<2; ++kk){
      short8 af[2], bfr[2];
      #pragma unroll
      for (int mi=0;mi<2;++mi)
        af[mi] = *(const short8*)&la[(wr*32 + mi*16 + lr)*64 + ((kk*32 + lg*8) ^ sw)];
      #pragma unroll
      for (int ni=0;ni<2;++ni)
        bfr[ni] = *(const short8*)&lb[(wc*32 + ni*16 + lr)*64 + ((kk*32 + lg*8) ^ sw)];
      #pragma unroll
      for (int mi=0;mi<2;++mi)
        #pragma unroll
        for (int ni=0;ni<2;++ni)
          acc[mi][ni] = __builtin_amdgcn_mfma_f32_16x16x32_bf16(af[mi], bfr[ni], acc[mi][ni], 0, 0, 0);
    }
    __syncthreads();
    cur ^= 1;
  }
  if constexpr (MODE==3){
    int nt = n0 >> 6;          // 0..47 ; uniform per block
    int kind = nt >> 4;        // 0=q 1=k 2=v
    int hh = nt & 15;
    #pragma unroll
    for (int mi=0;mi<2;++mi){
      int rb = m0 + wr*32 + mi*16 + lg*4;
      #pragma unroll
      for (int ni=0;ni<2;++ni){
        int d = wc*32 + ni*16 + lr;
        float bcol = bias[n0 + d];
        if (kind == 2){
          unsigned short pk[4];
          #pragma unroll
          for (int r=0;r<4;++r){
            float v = acc[mi][ni][r] + bcol;
            pk[r] = f2b(v);
            int t = rb + r;
            if (t < 513) vl[(size_t)(1024+t)*1024 + hh*64 + d] = v;
          }
          uint2 u2;
          u2.x = pk[0] | ((unsigned)pk[1]<<16);
          u2.y = pk[2] | ((unsigned)pk[3]<<16);
          *(uint2*)(vt + (size_t)(hh*64+d)*VTP + 1024 + rb) = u2;  // pad absorbs t>=513
        } else {
          int j = d >> 1;
          #pragma unroll
          for (int r=0;r<4;++r){
            float v = acc[mi][ni][r] + bcol;
            float p = __shfl_xor(v, 1);   // partner d^1 lives in lane lr^1
            int t = rb + r;
            int tc = (t < 513) ? t : 0;
            float c = cost[(tc<<5)+j], s = sint[(tc<<5)+j];
            float o = (d&1) ? (p*s + v*c) : (v*c - p*s);
            if (t < 513){
              if (kind == 0){
                qb16[(size_t)t*1024 + hh*64 + d] = f2b(o*0.125f); // pre-scale 1/8
              } else {
                size_t ko = (size_t)(1024+t)*1024 + hh*64 + d;
                kb16[ko] = f2b(o);
                kl[ko] = o;
              }
            }
          }
        }
      }
    }
  } else {
    float* Pz = P + (size_t)blockIdx.z*M*N;
    #pragma unroll
    for (int mi=0;mi<2;++mi){
      int rb = m0 + wr*32 + mi*16 + lg*4;
      #pragma unroll
      for (int ni=0;ni<2;++ni){
        int col = n0 + wc*32 + ni*16 + lr;
        float bcol = (MODE!=0) ? bias[col] : 0.f;
        #pragma unroll
        for (int r=0;r<4;++r){
          int row = rb + r;
          if (row < M){
            if constexpr (MODE==0){
              Pz[(size_t)row*N + col] = acc[mi][ni][r];
            } else {
              outh[(size_t)row*N + col] = f2b(gelu_f(acc[mi][ni][r] + bcol));
            }
          }
        }
      }
    }
  }
}

// ---------- split-K reduce + bias + residual(+LN->bf16); one block per row ----------
template<int KS, int DOLN>
__global__ __launch_bounds__(256) void reduce_ln_k(const float* __restrict__ P,
    const float* __restrict__ bias, float* __restrict__ x,
    const float* __restrict__ lnw, const float* __restrict__ lnb,
    unsigned short* __restrict__ outh){
  const int M = 513;
  int row = blockIdx.x;
  int tid = threadIdx.x;
  int c4 = tid<<2;
  float4 sv = *(const float4*)(P + (size_t)row*1024 + c4);
  #pragma unroll
  for (int z=1; z<KS; ++z){
    float4 t = *(const float4*)(P + (size_t)z*M*1024 + (size_t)row*1024 + c4);
    sv.x+=t.x; sv.y+=t.y; sv.z+=t.z; sv.w+=t.w;
  }
  float4 bv = *(const float4*)(bias + c4);
  float4 xv = *(const float4*)(x + (size_t)row*1024 + c4);
  xv.x += sv.x+bv.x; xv.y += sv.y+bv.y; xv.z += sv.z+bv.z; xv.w += sv.w+bv.w;
  *(float4*)(x + (size_t)row*1024 + c4) = xv;
  if constexpr (DOLN){
    float s  = xv.x+xv.y+xv.z+xv.w;
    float ss = xv.x*xv.x+xv.y*xv.y+xv.z*xv.z+xv.w*xv.w;
    for (int o=32;o;o>>=1){ s += __shfl_down(s,o); ss += __shfl_down(ss,o); }
    __shared__ float red[8];
    int wid = tid>>6;
    if ((tid&63)==0){ red[wid]=s; red[4+wid]=ss; }
    __syncthreads();
    if (tid==0){
      float ts = red[0]+red[1]+red[2]+red[3];
      float tss= red[4]+red[5]+red[6]+red[7];
      float mu = ts*(1.0f/1024.0f);
      float var= tss*(1.0f/1024.0f) - mu*mu;
      red[0]=mu; red[1]=rsqrtf(var + 1e-5f);
    }
    __syncthreads();
    float mu = red[0], rs = red[1];
    float4 wv = *(const float4*)(lnw + c4);
    float4 bb = *(const float4*)(lnb + c4);
    float o0 = (xv.x-mu)*rs*wv.x + bb.x;
    float o1 = (xv.y-mu)*rs*wv.y + bb.y;
    float o2 = (xv.z-mu)*rs*wv.z + bb.z;
    float o3 = (xv.w-mu)*rs*wv.w + bb.w;
    uint2 u;
    u.x = (unsigned)f2b(o0) | ((unsigned)f2b(o1)<<16);
    u.y = (unsigned)f2b(o2) | ((unsigned)f2b(o3)<<16);
    *(uint2*)(outh + (size_t)row*1024 + c4) = u;
  }
}

// ---------- BATCHED past KV: bf16 K buf + transposed V buf + fp32 cache-out ----------
__global__ __launch_bounds__(256) void past16_k(const float* __restrict__ kvin,
    unsigned short* __restrict__ kb, unsigned short* __restrict__ vt,
    float* __restrict__ kvout){
  __shared__ float s[64][68];
  int l = blockIdx.z;
  int hh = blockIdx.x, t0 = blockIdx.y*64;
  const float* kvK = kvin + (size_t)l*2097152;
  const float* kvV = kvK + 1048576;
  unsigned short* kbL = kb + (size_t)l*KVL;
  unsigned short* vtL = vt + (size_t)l*KVL;
  float* kl = kvout + (size_t)(2*l)  *KV_LS_STRIDE;
  float* vl = kvout + (size_t)(2*l+1)*KV_LS_STRIDE;
  int tid = threadIdx.x;
  int row = tid>>4, c4 = (tid&15)<<2;
  #pragma unroll
  for (int p=0;p<4;++p){
    int rr = row + p*16;
    size_t off = (size_t)(t0+rr)*1024 + hh*64 + c4;
    float4 v = *(const float4*)(kvK + off);
    uint2 u;
    u.x = (unsigned)f2b(v.x) | ((unsigned)f2b(v.y)<<16);
    u.y = (unsigned)f2b(v.z) | ((unsigned)f2b(v.w)<<16);
    *(uint2*)(kbL + off) = u;
    kl[off]=v.x; kl[off+1]=v.y; kl[off+2]=v.z; kl[off+3]=v.w;
    float4 w = *(const float4*)(kvV + off);
    *(float4*)&s[rr][c4] = w;
    vl[off]=w.x; vl[off+1]=w.y; vl[off+2]=w.z; vl[off+3]=w.w;
  }
  __syncthreads();
  int n = tid>>2, ks = tid&3;
  unsigned short tmp[16];
  #pragma unroll
  for (int j=0;j<16;++j) tmp[j] = f2b(s[ks*16+j][n]);
  size_t ob = (size_t)(hh*64+n)*VTP + t0 + ks*16;
  uint4 lo, hi;
  lo.x = tmp[0] | ((unsigned)tmp[1]<<16);  lo.y = tmp[2] | ((unsigned)tmp[3]<<16);
  lo.z = tmp[4] | ((unsigned)tmp[5]<<16);  lo.w = tmp[6] | ((unsigned)tmp[7]<<16);
  hi.x = tmp[8] | ((unsigned)tmp[9]<<16);  hi.y = tmp[10]| ((unsigned)tmp[11]<<16);
  hi.z = tmp[12]| ((unsigned)tmp[13]<<16); hi.w = tmp[14]| ((unsigned)tmp[15]<<16);
  *(uint4*)(vtL + ob)     = lo;
  *(uint4*)(vtL + ob + 8) = hi;
}

// ---------- MFMA flash attention: zero-LDS, swapped-operand, packed K=32 PV ----------
static __device__ __forceinline__ f32x4 mfma32(short8 a, short8 b, f32x4 c){
  return __builtin_amdgcn_mfma_f32_16x16x32_bf16(a, b, c, 0, 0, 0);
}

__global__ __launch_bounds__(128) void attn_k(const unsigned short* __restrict__ qb,
    const unsigned short* __restrict__ kb, const unsigned short* __restrict__ vt,
    float* __restrict__ Oc, float* __restrict__ ml){
  const int T=513, Tkv=1537, past=1024;
  int hh = blockIdx.x, bt = blockIdx.y, ch = blockIdx.z;
  int wv = threadIdx.x >> 6, l = threadIdx.x & 63;
  int g = l >> 4, lr = l & 15;
  int q0 = bt*32 + wv*16;
  int gq = q0 + lr;
  const unsigned short* qp = qb + (size_t)gq*1024 + hh*64 + g*8;
  short8 qf0 = *(const short8*)qp;
  short8 qf1 = *(const short8*)(qp+32);
  f32x4 acc_o[4];
  #pragma unroll
  for (int i=0;i<4;++i) acc_o[i] = (f32x4){0.f,0.f,0.f,0.f};
  float m_run = -1e30f, l_run = 0.f;
  int kend_w = past + q0 + 16; if (kend_w > Tkv) kend_w = Tkv;
  int kstart = ch*256;
  int kend = (ch==NCH-1) ? kend_w : ((ch+1)*256 < kend_w ? (ch+1)*256 : kend_w);
  for (int kt0 = kstart; kt0 < kend; kt0 += 64){
    float p[16];
    #pragma unroll
    for (int st=0; st<4; ++st){
      const unsigned short* kp = kb + (size_t)(kt0+st*16+lr)*1024 + hh*64 + g*8;
      short8 kf0 = *(const short8*)kp;
      short8 kf1 = *(const short8*)(kp+32);
      f32x4 s4 = (f32x4){0.f,0.f,0.f,0.f};
      s4 = mfma32(kf0, qf0, s4);
      s4 = mfma32(kf1, qf1, s4);
      #pragma unroll
      for (int r=0;r<4;++r) p[st*4+r] = s4[r];
    }
    if (kt0 + 63 > past + q0 + 15 || kt0 + 63 >= Tkv){
      #pragma unroll
      for (int st=0; st<4; ++st)
        #pragma unroll
        for (int r=0;r<4;++r){
          int kt = kt0 + st*16 + g*4 + r;
          if (kt > past + gq || kt >= Tkv) p[st*4+r] = -1e30f;
        }
    }
    float tmax = p[0];
    #pragma unroll
    for (int i=1;i<16;++i) tmax = fmaxf(tmax, p[i]);
    tmax = fmaxf(tmax, __shfl_xor(tmax,16));
    tmax = fmaxf(tmax, __shfl_xor(tmax,32));
    float m_new = fmaxf(m_run, tmax);
    float sc = __expf(m_run - m_new);
    float psum = 0.f;
    #pragma unroll
    for (int i=0;i<16;++i){ p[i] = __expf(p[i] - m_new); psum += p[i]; }
    psum += __shfl_xor(psum,16); psum += __shfl_xor(psum,32);
    l_run = l_run*sc + psum;
    m_run = m_new;
    #pragma unroll
    for (int db=0;db<4;++db){
      acc_o[db][0]*=sc; acc_o[db][1]*=sc; acc_o[db][2]*=sc; acc_o[db][3]*=sc;
    }
    short8 pf[2];
    #pragma unroll
    for (int sp=0; sp<2; ++sp){
      union { short8 s8; unsigned int u[4]; } pu;
      pu.u[0] = (unsigned)f2b(p[sp*8+0]) | ((unsigned)f2b(p[sp*8+1])<<16);
      pu.u[1] = (unsigned)f2b(p[sp*8+2]) | ((unsigned)f2b(p[sp*8+3])<<16);
      pu.u[2] = (unsigned)f2b(p[sp*8+4]) | ((unsigned)f2b(p[sp*8+5])<<16);
      pu.u[3] = (unsigned)f2b(p[sp*8+6]) | ((unsigned)f2b(p[sp*8+7])<<16);
      pf[sp] = pu.s8;
    }
    #pragma unroll
    for (int sp=0; sp<2; ++sp){
      #pragma unroll
      for (int db=0; db<4; ++db){
        const unsigned short* vp = vt + (size_t)(hh*64 + db*16 + lr)*VTP + kt0 + sp*32 + g*4;
        short4v va0 = *(const short4v*)vp;
        short4v va1 = *(const short4v*)(vp + 16);
        short8 va = (short8){va0[0],va0[1],va0[2],va0[3],va1[0],va1[1],va1[2],va1[3]};
        acc_o[db] = mfma32(va, pf[sp], acc_o[db]);
      }
    }
  }
  if (gq < T){
    size_t ob = ((size_t)(ch*16+hh)*544 + gq)*64;
    #pragma unroll
    for (int db=0;db<4;++db)
      *(float4*)(Oc + ob + db*16 + g*4) = make_float4(acc_o[db][0],acc_o[db][1],acc_o[db][2],acc_o[db][3]);
    if (g==0){
      size_t mo = ((size_t)(ch*16+hh)*544 + gq)*2;
      ml[mo] = m_run; ml[mo+1] = l_run;
    }
  }
}

// ---------- combine NCH KV chunks -> bf16 attn out ----------
__global__ __launch_bounds__(256) void attn_comb_k(const float* __restrict__ Oc,
    const float* __restrict__ ml, unsigned short* __restrict__ obb){
  int qg = blockIdx.x;
  int t = threadIdx.x;
  int hh = t>>4, d4 = (t&15)<<2;
  float m[NCH], lv[NCH];
  float mm = -1e30f;
  #pragma unroll
  for (int c=0;c<NCH;++c){
    size_t mo = ((size_t)(c*16+hh)*544 + qg)*2;
    m[c]=ml[mo]; lv[c]=ml[mo+1];
    mm = fmaxf(mm, m[c]);
  }
  float w[NCH], denom = 0.f;
  #pragma unroll
  for (int c=0;c<NCH;++c){ w[c] = __expf(m[c]-mm); denom += lv[c]*w[c]; }
  float inv = 1.0f/denom;
  float r0=0.f,r1=0.f,r2=0.f,r3=0.f;
  #pragma unroll
  for (int c=0;c<NCH;++c){
    float4 o = *(const float4*)(Oc + (((size_t)(c*16+hh)*544+qg)*64 + d4));
    r0 += o.x*w[c]; r1 += o.y*w[c]; r2 += o.z*w[c]; r3 += o.w*w[c];
  }
  r0*=inv; r1*=inv; r2*=inv; r3*=inv;
  uint2 u;
  u.x = (unsigned)f2b(r0) | ((unsigned)f2b(r1)<<16);
  u.y = (unsigned)f2b(r2) | ((unsigned)f2b(r3)<<16);
  *(uint2*)(obb + (size_t)qg*1024 + hh*64 + d4) = u;
}

// ---------- eos head + cache_len ----------
__global__ __launch_bounds__(256) void eos_tail_k(const float* __restrict__ tout,
    const float* __restrict__ Weos, const float* __restrict__ beos,
    const int* __restrict__ clen, float* __restrict__ out){
  int tid = threadIdx.x;
  float s = 0.f;
  for (int i=tid;i<1024;i+=256) s += tout[i]*Weos[i];
  for (int o=32;o;o>>=1) s += __shfl_down(s,o);
  __shared__ float red[4];
  if ((tid&63)==0) red[tid>>6] = s;
  __syncthreads();
  if (tid==0){
    float v = red[0]+red[1]+red[2]+red[3] + beos[0];
    out[512] = (v > -4.0f) ? 1.0f : 0.0f;
    out[CLEN_OUT_IDX] = (float)(clen[0] + 513);
  }
}

// ---------- flow MLP (K-split) ----------
__global__ __launch_bounds__(256) void flow1_k(const float* __restrict__ tout,
    const float* __restrict__ noise, const float* __restrict__ Wf1,
    const float* __restrict__ bf1, float* __restrict__ fh){
  __shared__ float red[16][17];
  int t = threadIdx.x;
  int n = blockIdx.x*16 + (t&15), ks = t>>4;
  float s = 0.f;
  for (int k=ks*96; k<ks*96+96; ++k){
    float in = (k < 1024) ? tout[k] : noise[k-1024];
    size_t krow = (k < 1024) ? (size_t)k : (size_t)(k+2);
    s += in * Wf1[krow*2048 + n];
  }
  red[ks][t&15] = s;
  __syncthreads();
  if (t < 16){
    int nn = blockIdx.x*16 + t;
    float acc = bf1[nn] + Wf1[(size_t)1025*2048 + nn];  // t_time=1
    #pragma unroll
    for (int j=0;j<16;++j) acc += red[j][t];
    fh[nn] = gelu_f(acc);
  }
}

__global__ __launch_bounds__(256) void flow2_k(const float* __restrict__ fh,
    const float* __restrict__ noise, const float* __restrict__ Wf2,
    const float* __restrict__ bf2, float* __restrict__ out){
  __shared__ float red[16][17];
  int t = threadIdx.x;
  int n = blockIdx.x*16 + (t&15), ks = t>>4;
  float s = 0.f;
  for (int k=ks*128; k<ks*128+128; ++k) s += fh[k]*Wf2[(size_t)k*512 + n];
  red[ks][t&15] = s;
  __syncthreads();
  if (t < 16){
    int nn = blockIdx.x*16 + t;
    float acc = bf2[nn];
    #pragma unroll
    for (int j=0;j<16;++j) acc += red[j][t];
    out[nn] = noise[nn] + acc;
  }
}

extern "C" void kernel_launch(void* const* d_in, const int* in_sizes, int n_in,
                              void* d_out, int out_size, void* d_ws, size_t ws_size,
                              hipStream_t stream) {
  const float* text  = (const float*)d_in[0];
  const float* prevl = (const float*)d_in[1];
  const float* kvin  = (const float*)d_in[2];
  const int*   clen  = (const int*)  d_in[3];
  const float* noise = (const float*)d_in[4];
  const float* bos   = (const float*)d_in[5];
  const float* Win   = (const float*)d_in[6];
  const float* bin   = (const float*)d_in[7];
  const float* ln1w  = (const float*)d_in[8];
  const float* ln1b  = (const float*)d_in[9];
  const float* Wqkv  = (const float*)d_in[10];
  const float* bqkv  = (const float*)d_in[11];
  const float* Wo    = (const float*)d_in[12];
  const float* bo    = (const float*)d_in[13];
  const float* ln2w  = (const float*)d_in[14];
  const float* ln2b  = (const float*)d_in[15];
  const float* W1    = (const float*)d_in[16];
  const float* b1    = (const float*)d_in[17];
  const float* W2    = (const float*)d_in[18];
  const float* b2    = (const float*)d_in[19];
  const float* onw   = (const float*)d_in[20];
  const float* onb   = (const float*)d_in[21];
  const float* Weos  = (const float*)d_in[22];
  const float* beos  = (const float*)d_in[23];
  const float* Wf1   = (const float*)d_in[24];
  const float* bf1   = (const float*)d_in[25];
  const float* Wf2   = (const float*)d_in[26];
  const float* bf2   = (const float*)d_in[27];

  float* out   = (float*)d_out;
  float* kvout = out + KV_OUT_OFF;
  float* ws = (float*)d_ws;
  float* x    = ws;                          // 525312
  float* Pbuf = x    + 525312;               // 4202496
  float* Oc   = Pbuf + 4202496;              // NCH*16*544*64 = 3342336
  float* mlb  = Oc   + 3342336;              // NCH*16*544*2 = 104448
  float* cost = mlb  + 104448;               // 16416
  float* sint = cost + 16416;                // 16416
  float* tout = sint + 16416;                // 1024
  float* fh   = tout + 1024;                 // 2048
  unsigned short* hb   = (unsigned short*)(fh + 2048); // 640*1024
  unsigned short* gb   = hb   + 655360;      // 640*4096
  unsigned short* obb  = gb   + 2621440;     // 640*1024
  unsigned short* qb16 = obb  + 655360;      // 544*1024
  unsigned short* kb16 = qb16 + 557056;      // 16 * KVL
  unsigned short* vt16 = kb16 + (size_t)16*KVL;
  unsigned short* qkvT = vt16 + (size_t)16*KVL;          // 16*3072*1024
  unsigned short* woT  = qkvT + (size_t)16*3145728;      // 16*1024*1024
  unsigned short* w1T  = woT  + (size_t)16*1048576;      // 16*4096*1024
  unsigned short* w2T  = w1T  + (size_t)16*4194304;      // 16*1024*4096

  // prologue
  past16_k<<<dim3(16,16,16),256,0,stream>>>(kvin, kb16, vt16, kvout);
  wtrans_k<<<dim3(48,16,16),256,0,stream>>>(Wqkv, qkvT, 1024, 3072);
  wtrans_k<<<dim3(16,16,16),256,0,stream>>>(Wo,   woT,  1024, 1024);
  wtrans_k<<<dim3(64,16,16),256,0,stream>>>(W1,   w1T,  1024, 4096);
  wtrans_k<<<dim3(16,64,16),256,0,stream>>>(W2,   w2T,  4096, 1024);
  copy_text_k<<<512,256,0,stream>>>((const float4*)text, (float4*)x);
  build512_k<<<64,256,0,stream>>>(prevl, bos, Win, bin, x);
  rope_tab_k<<<65,256,0,stream>>>(cost, sint, clen);
  ln_k<1><<<513,256,0,stream>>>(x, ln1w, ln1b, nullptr, hb, 513);

  for (int l=0; l<16; ++l){
    float* kl = kvout + (size_t)(2*l)  *KV_LS_STRIDE;
    float* vl = kvout + (size_t)(2*l+1)*KV_LS_STRIDE;
    unsigned short* kbL = kb16 + (size_t)l*KVL;
    unsigned short* vtL = vt16 + (size_t)l*KVL;
    // QKV: fused RoPE/scatter/V-transpose epilogue (MODE 3), 432 blocks
    mgemm64_k<3><<<dim3(48,9),256,0,stream>>>(hb, qkvT+(size_t)l*3145728, nullptr,
        bqkv+(size_t)l*3072, nullptr, 513, 3072, 1024, 1024,
        cost, sint, qb16, kbL, vtL, kl, vl);
    attn_k<<<dim3(16,17,NCH),128,0,stream>>>(qb16, kbL, vtL, Oc, mlb);
    attn_comb_k<<<513,256,0,stream>>>(Oc, mlb, obb);
    // Wo: split-K=4 (576 blocks) + reduce+residual+LN2
    mgemm64_k<0><<<dim3(16,9,4),256,0,stream>>>(obb, woT+(size_t)l*1048576, Pbuf,
        nullptr, nullptr, 513, 1024, 1024, 256,
        nullptr, nullptr, nullptr, nullptr, nullptr, nullptr, nullptr);
    reduce_ln_k<4,1><<<513,256,0,stream>>>(Pbuf, bo+(size_t)l*1024, x,
        ln2w+(size_t)l*1024, ln2b+(size_t)l*1024, hb);
    // FF1: full-K + bias + gelu -> gb bf16 (576 blocks)
    mgemm64_k<2><<<dim3(64,9),256,0,stream>>>(hb, w1T+(size_t)l*4194304, nullptr,
        b1+(size_t)l*4096, gb, 513, 4096, 1024, 1024,
        nullptr, nullptr, nullptr, nullptr, nullptr, nullptr, nullptr);
    // FF2: split-K=4 (576 blocks) + reduce+residual+next LN1
    mgemm64_k<0><<<dim3(16,9,4),256,0,stream>>>(gb, w2T+(size_t)l*4194304, Pbuf,
        nullptr, nullptr, 513, 1024, 4096, 1024,
        nullptr, nullptr, nullptr, nullptr, nullptr, nullptr, nullptr);
    if (l < 15)
      reduce_ln_k<4,1><<<513,256,0,stream>>>(Pbuf, b2+(size_t)l*1024, x,
          ln1w+(size_t)(l+1)*1024, ln1b+(size_t)(l+1)*1024, hb);
    else
      reduce_ln_k<4,0><<<513,256,0,stream>>>(Pbuf, b2+(size_t)l*1024, x,
          nullptr, nullptr, nullptr);
  }

  ln_k<0><<<1,256,0,stream>>>(x + (size_t)512*1024, onw, onb, tout, nullptr, 1);
  eos_tail_k<<<1,256,0,stream>>>(tout, Weos, beos, clen, out);
  flow1_k<<<128,256,0,stream>>>(tout, noise, Wf1, bf1, fh);
  flow2_k<<<32,256,0,stream>>>(fh, noise, Wf2, bf2, out);
}